// Round 4
// baseline (318.823 us; speedup 1.0000x reference)
//
#include <hip/hip_runtime.h>
#include <math.h>

#define N 1024
#define NB 256
#define KD 5

// ---------------- wave (64-lane) reductions ----------------
__device__ __forceinline__ float wred_sum(float v){
#pragma unroll
  for (int off = 32; off > 0; off >>= 1) v += __shfl_down(v, off);
  return v;
}
__device__ __forceinline__ float wred_max(float v){
#pragma unroll
  for (int off = 32; off > 0; off >>= 1) v = fmaxf(v, __shfl_down(v, off));
  return v;
}

// ---- block-wide (1024 thr, 16 waves) reductions; result broadcast ----
__device__ __forceinline__ float bsum1(float v, float* s64){
  float w = wred_sum(v);
  __syncthreads();
  if ((threadIdx.x & 63) == 0) s64[threadIdx.x >> 6] = w;
  __syncthreads();
  float r = 0.f;
#pragma unroll
  for (int i = 0; i < 16; ++i) r += s64[i];
  return r;
}
__device__ __forceinline__ void bsum4(float v[4], float* s64){
  float w0 = wred_sum(v[0]), w1 = wred_sum(v[1]), w2 = wred_sum(v[2]), w3 = wred_sum(v[3]);
  __syncthreads();
  int wv = threadIdx.x >> 6;
  if ((threadIdx.x & 63) == 0){ s64[wv*4] = w0; s64[wv*4+1] = w1; s64[wv*4+2] = w2; s64[wv*4+3] = w3; }
  __syncthreads();
  float r0 = 0.f, r1 = 0.f, r2 = 0.f, r3 = 0.f;
#pragma unroll
  for (int i = 0; i < 16; ++i){ r0 += s64[i*4]; r1 += s64[i*4+1]; r2 += s64[i*4+2]; r3 += s64[i*4+3]; }
  v[0] = r0; v[1] = r1; v[2] = r2; v[3] = r3;
}
__device__ __forceinline__ void bmax4(float v[4], float* s64){
  float w0 = wred_max(v[0]), w1 = wred_max(v[1]), w2 = wred_max(v[2]), w3 = wred_max(v[3]);
  __syncthreads();
  int wv = threadIdx.x >> 6;
  if ((threadIdx.x & 63) == 0){ s64[wv*4] = w0; s64[wv*4+1] = w1; s64[wv*4+2] = w2; s64[wv*4+3] = w3; }
  __syncthreads();
  float r0 = s64[0], r1 = s64[1], r2 = s64[2], r3 = s64[3];
#pragma unroll
  for (int i = 1; i < 16; ++i){
    r0 = fmaxf(r0, s64[i*4]);   r1 = fmaxf(r1, s64[i*4+1]);
    r2 = fmaxf(r2, s64[i*4+2]); r3 = fmaxf(r3, s64[i*4+3]);
  }
  v[0] = r0; v[1] = r1; v[2] = r2; v[3] = r3;
}

// ---------------- grid barrier: 256 co-resident blocks, fresh slot per use ----------------
__device__ __forceinline__ void gbar(int* c){
  __syncthreads();
  if (threadIdx.x == 0){
    __threadfence();                 // release (agent): drain + wb L2
    atomicAdd(c, 1);                 // device-scope
    while (__hip_atomic_load(c, __ATOMIC_RELAXED, __HIP_MEMORY_SCOPE_AGENT) < NB)
      __builtin_amdgcn_s_sleep(2);
    __threadfence();                 // acquire
  }
  __syncthreads();
}

// ---------------- the persistent fused kernel ----------------
// Block B owns rows 4B..4B+3; thread t owns column t. 1 block/CU, 16 waves.
extern "C" __global__ void __launch_bounds__(1024)
gm2(const int* __restrict__ adj1, const int* __restrict__ adj2,
    const float* __restrict__ roW1, const float* __restrict__ roB1,
    const float* __restrict__ roW2, const float* __restrict__ roB2,
    const float* __restrict__ fW1,  const float* __restrict__ fB1,
    const float* __restrict__ fW2,  const float* __restrict__ fB2,
    float* __restrict__ t0, float* __restrict__ t1,
    float* __restrict__ Pp,          // [10][8][N] pre-zeroed column-partial slots
    float* __restrict__ Rg,          // [N] published row factors
    int*   __restrict__ cnt,         // [16] pre-zeroed barrier counters
    float* __restrict__ out)
{
  __shared__ __align__(16) float rows20[20][N];   // 80 KB staging, conflict-free layout
  __shared__ float lc[N];                         // log C3
  __shared__ float s64[64];
  __shared__ float tab5[8];
  __shared__ float sAv[4];
  __shared__ float ux[64], udA[64], udB[64], xs_s[64], dA_s[64], dB_s[64];
  __shared__ float A_tab[65], B_tab[65], sA0B0[2];

  const int t = threadIdx.x, B = blockIdx.x;
  int bar = 0;

  // ---- per-thread adjacency (column t) ----
  int a2[KD];
#pragma unroll
  for (int c = 0; c < KD; ++c) a2[c] = adj2[t * KD + c];

  // ---- ttheta: every block computes it redundantly (no sync needed) ----
  int v1[KD];
#pragma unroll
  for (int r = 0; r < KD; ++r) v1[r] = adj1[t * KD + r];
  int c1 = 0;
#pragma unroll
  for (int r = 0; r < KD; ++r){
    bool dup = false;
#pragma unroll
    for (int s = 0; s < r; ++s) dup = dup || (v1[s] == v1[r]);
    c1 += dup ? 0 : 1;
  }
  const float tt = bsum1((float)c1, s64) * (1.0f / 1024.0f);

  // degree of column t in G2
  int c2 = 0;
#pragma unroll
  for (int r = 0; r < KD; ++r){
    bool dup = false;
#pragma unroll
    for (int s = 0; s < r; ++s) dup = dup || (a2[s] == a2[r]);
    c2 += dup ? 0 : 1;
  }
  // degrees of the block's 4 owned G1 rows (uniform scalar loads)
  float d1r[4];
#pragma unroll
  for (int r = 0; r < 4; ++r){
    int w[KD];
#pragma unroll
    for (int s = 0; s < KD; ++s) w[s] = adj1[(4 * B + r) * KD + s];
    int cc = 0;
#pragma unroll
    for (int x = 0; x < KD; ++x){
      bool dup = false;
#pragma unroll
      for (int s = 0; s < x; ++s) dup = dup || (w[s] == w[x]);
      cc += dup ? 0 : 1;
    }
    d1r[r] = (float)cc;
  }

  // ---- layer-0 MLP: 5 distinct inputs -> exact table ----
  if (t < KD){
    float x = -(float)t / tt;
    float acc = roB2[0];
    for (int k = 0; k < 64; ++k){
      float h = fmaxf(fmaf(x, roW1[k], roB1[k]), 0.f);
      acc = fmaf(h, roW2[k], acc);
    }
    tab5[t] = acc;
  }
  __syncthreads();

  // ---- producer (layer-0 row softmax): t0, E regs, R regs, C1 partials ----
  float E[4], R[4], q4[4], y[4], rm[4];
#pragma unroll
  for (int r = 0; r < 4; ++r){ y[r] = tab5[(int)fabsf(d1r[r] - (float)c2)]; rm[r] = y[r]; }
  bmax4(rm, s64);
#pragma unroll
  for (int r = 0; r < 4; ++r){
    float tv = y[r] - rm[r];
    t0[(size_t)(4 * B + r) * N + t] = tv;
    E[r] = expf(tv);
    q4[r] = E[r];
  }
  bsum4(q4, s64);
  {
    float cp = 0.f;
#pragma unroll
    for (int r = 0; r < 4; ++r){ R[r] = 1.0f / q4[r]; cp = fmaf(E[r], R[r], cp); }
    atomicAdd(&Pp[(size_t)(0 * 8 + (B & 7)) * N + t], cp);
  }

  const float* tcur = t0;
  float* tnx = t1;
  float yF[4], rmF[4], rsF[4];

  for (int li = 0; li < 3; ++li){
    // ---- sinkhorn column syncs: C1, C2, C3 (row renorms are block-local) ----
#pragma unroll 1
    for (int pass = 0; pass < 3; ++pass){
      gbar(&cnt[bar]); ++bar;
      int pb = (3 * li + pass) * 8;
      float C = 0.f;
#pragma unroll
      for (int k = 0; k < 8; ++k) C += Pp[(size_t)(pb + k) * N + t];
      if (pass < 2){
        float iC = 1.0f / C;
#pragma unroll
        for (int r = 0; r < 4; ++r) q4[r] = E[r] * iC;
        bsum4(q4, s64);
        float cp = 0.f;
#pragma unroll
        for (int r = 0; r < 4; ++r){ R[r] = 1.0f / q4[r]; cp = fmaf(E[r], R[r], cp); }
        if (pass == 1 && t < 4) Rg[4 * B + t] = R[t];       // publish final R
        atomicAdd(&Pp[(size_t)(pb + 8 + (B & 7)) * N + t], cp);
      } else {
        lc[t] = logf(C);                                     // log C3 into LDS
      }
    }

    // ---- X1 phase setup: A-terms, PWL tables, stage 20 gathered rows ----
    if (t < 4){
      int a = 4 * B + t;
      float s = 5.0f * logf(1536.0f);
#pragma unroll
      for (int r = 0; r < KD; ++r) s += logf(Rg[adj1[a * KD + r]]);
      sAv[t] = s;
    }
    const float* w1g = (li < 2) ? (roW1 + (li + 1) * 64) : fW1;
    const float* b1g = (li < 2) ? (roB1 + (li + 1) * 64) : fB1;
    const float* w2g = (li < 2) ? (roW2 + (li + 1) * 64) : fW2;
    const float* b2g = (li < 2) ? (roB2 + (li + 1))      : fB2;
    if (t < 64){
      float w1 = w1g[t], bb = b1g[t], w2 = w2g[t];
      float xk, sdA, sdB, a0t = 0.f, b0t = 0.f;
      if (w1 != 0.f){
        xk = -bb / w1;
        float dA = w1 * w2, dB = bb * w2;
        if (w1 > 0.f){ sdA = dA;  sdB = dB; }
        else         { sdA = -dA; sdB = -dB; a0t = dA; b0t = dB; }
      } else {
        xk = 3.0e38f; sdA = 0.f; sdB = 0.f;
        b0t = fmaxf(bb, 0.f) * w2;
      }
      ux[t] = xk; udA[t] = sdA; udB[t] = sdB;
      float A0 = wred_sum(a0t);
      float B0 = wred_sum(b0t);
      if (t == 0){ sA0B0[0] = A0; sA0B0[1] = B0 + b2g[0]; }
    }
#pragma unroll
    for (int r2 = 0; r2 < 20; ++r2){
      int src = adj1[(4 * B + (r2 / 5)) * KD + (r2 % 5)];    // uniform scalar
      rows20[r2][t] = tcur[(size_t)src * N + t];
    }
    __syncthreads();
    if (t < 64){
      float xk = ux[t]; int rank = 0;
      for (int j = 0; j < 64; ++j){
        float xj = ux[j];
        rank += (xj < xk || (xj == xk && j < t)) ? 1 : 0;
      }
      xs_s[rank] = ux[t]; dA_s[rank] = udA[t]; dB_s[rank] = udB[t];
    }
    __syncthreads();
    if (t < 65){
      float sa = sA0B0[0], sb = sA0B0[1];
      for (int r = 0; r < t; ++r){ sa += dA_s[r]; sb += dB_s[r]; }
      A_tab[t] = sa; B_tab[t] = sb;
    }
    __syncthreads();

    // ---- DP assignment-max + PWL MLP for the 4 owned rows ----
    float Bvl = 0.f;
#pragma unroll
    for (int c = 0; c < KD; ++c) Bvl -= lc[a2[c]];
#pragma unroll 1
    for (int rr = 0; rr < 4; ++rr){
      float t5[KD][KD];
#pragma unroll
      for (int r = 0; r < KD; ++r)
#pragma unroll
        for (int c = 0; c < KD; ++c) t5[r][c] = rows20[rr * 5 + r][a2[c]];
      float f[32];
      f[0] = 0.f;
#pragma unroll
      for (int m = 1; m < 32; ++m){
        int r = __popc(m) - 1;
        float best = -3.0e38f;
#pragma unroll
        for (int c = 0; c < KD; ++c)
          if (m & (1 << c)) best = fmaxf(best, f[m ^ (1 << c)] + t5[r][c]);
        f[m] = best;
      }
      float X1v = sAv[rr] + Bvl + f[31];
      float x = (li < 2) ? (X1v / tt) : X1v;
      int seg = 0;
#pragma unroll
      for (int s = 64; s; s >>= 1)
        if (seg + s <= 64 && xs_s[seg + s - 1] <= x) seg += s;
      y[rr] = fmaf(A_tab[seg], x, B_tab[seg]);
      rm[rr] = y[rr];
    }
    bmax4(rm, s64);
    if (li < 2){
#pragma unroll
      for (int r = 0; r < 4; ++r){
        float tv = y[r] - rm[r];
        tnx[(size_t)(4 * B + r) * N + t] = tv;
        E[r] = expf(tv);
        q4[r] = E[r];
      }
      bsum4(q4, s64);
      float cp = 0.f;
#pragma unroll
      for (int r = 0; r < 4; ++r){ R[r] = 1.0f / q4[r]; cp = fmaf(E[r], R[r], cp); }
      atomicAdd(&Pp[(size_t)((3 * li + 3) * 8 + (B & 7)) * N + t], cp);
      const float* tmp = tcur; tcur = tnx; tnx = (float*)tmp;
    } else {
      float cp = 0.f;
#pragma unroll
      for (int r = 0; r < 4; ++r){
        yF[r] = y[r]; rmF[r] = rm[r];
        q4[r] = expf(y[r] - rm[r]);
        cp += expf(y[r]);
      }
      bsum4(q4, s64);
#pragma unroll
      for (int r = 0; r < 4; ++r) rsF[r] = q4[r];
      atomicAdd(&Pp[(size_t)(9 * 8 + (B & 7)) * N + t], cp);
    }
  }

  // ---- final: column softmax denominators + combine (all row state in regs) ----
  gbar(&cnt[bar]); ++bar;
  float CF = 0.f;
#pragma unroll
  for (int k = 0; k < 8; ++k) CF += Pp[(size_t)(72 + k) * N + t];
  float iCF = 1.0f / CF;
#pragma unroll
  for (int r = 0; r < 4; ++r){
    float v = 0.5f * (expf(yF[r] - rmF[r]) / rsF[r] + expf(yF[r]) * iCF);
    out[(size_t)(4 * B + r) * N + t] = v;
  }
}

extern "C" void kernel_launch(void* const* d_in, const int* in_sizes, int n_in,
                              void* d_out, int out_size, void* d_ws, size_t ws_size,
                              hipStream_t stream){
  (void)in_sizes; (void)n_in; (void)out_size; (void)ws_size;
  const int*   adj1 = (const int*)d_in[2];
  const int*   adj2 = (const int*)d_in[3];
  const float* roW1 = (const float*)d_in[4];
  const float* roB1 = (const float*)d_in[5];
  const float* roW2 = (const float*)d_in[6];
  const float* roB2 = (const float*)d_in[7];
  const float* fW1  = (const float*)d_in[8];
  const float* fB1  = (const float*)d_in[9];
  const float* fW2  = (const float*)d_in[10];
  const float* fB2  = (const float*)d_in[11];
  float* out = (float*)d_out;

  // ws: t0 (4MB) | t1 (4MB) | Pp 10*8*N (320KB) | Rg N | cnt 16 ints
  float* t0 = (float*)d_ws;
  float* t1 = t0 + (size_t)N * N;
  float* Pp = t1 + (size_t)N * N;
  float* Rg = Pp + (size_t)10 * 8 * N;
  int*  cnt = (int*)(Rg + N);

  // one memset zeroes all partial slots + barrier counters (Rg always written first)
  hipMemsetAsync(Pp, 0, (10 * 8 * N + N) * sizeof(float) + 16 * sizeof(int), stream);
  gm2<<<NB, 1024, 0, stream>>>(adj1, adj2, roW1, roB1, roW2, roB2,
                               fW1, fB1, fW2, fB2,
                               t0, t1, Pp, Rg, cnt, out);
}

// Round 5
// 239.149 us; speedup vs baseline: 1.3332x; 1.3332x over previous
//
#include <hip/hip_runtime.h>
#include <math.h>

#define N 1024
#define NB 256
#define KD 5

// ---------------- coherent (MALL-level) load/store helpers ----------------
__device__ __forceinline__ float load_sc(const float* p){
  return __hip_atomic_load(p, __ATOMIC_RELAXED, __HIP_MEMORY_SCOPE_AGENT);
}
__device__ __forceinline__ void store_sc(float* p, float v){
  __hip_atomic_store(p, v, __ATOMIC_RELAXED, __HIP_MEMORY_SCOPE_AGENT);
}

// ---------------- wave (64-lane) reductions ----------------
__device__ __forceinline__ float wred_sum(float v){
#pragma unroll
  for (int off = 32; off > 0; off >>= 1) v += __shfl_down(v, off);
  return v;
}
__device__ __forceinline__ float wred_max(float v){
#pragma unroll
  for (int off = 32; off > 0; off >>= 1) v = fmaxf(v, __shfl_down(v, off));
  return v;
}
__device__ __forceinline__ float bsum1(float v, float* s64){
  float w = wred_sum(v);
  __syncthreads();
  if ((threadIdx.x & 63) == 0) s64[threadIdx.x >> 6] = w;
  __syncthreads();
  float r = 0.f;
#pragma unroll
  for (int i = 0; i < 16; ++i) r += s64[i];
  return r;
}
__device__ __forceinline__ void bsum4(float v[4], float* s64){
  float w0 = wred_sum(v[0]), w1 = wred_sum(v[1]), w2 = wred_sum(v[2]), w3 = wred_sum(v[3]);
  __syncthreads();
  int wv = threadIdx.x >> 6;
  if ((threadIdx.x & 63) == 0){ s64[wv*4] = w0; s64[wv*4+1] = w1; s64[wv*4+2] = w2; s64[wv*4+3] = w3; }
  __syncthreads();
  float r0 = 0.f, r1 = 0.f, r2 = 0.f, r3 = 0.f;
#pragma unroll
  for (int i = 0; i < 16; ++i){ r0 += s64[i*4]; r1 += s64[i*4+1]; r2 += s64[i*4+2]; r3 += s64[i*4+3]; }
  v[0] = r0; v[1] = r1; v[2] = r2; v[3] = r3;
}
__device__ __forceinline__ void bmax4(float v[4], float* s64){
  float w0 = wred_max(v[0]), w1 = wred_max(v[1]), w2 = wred_max(v[2]), w3 = wred_max(v[3]);
  __syncthreads();
  int wv = threadIdx.x >> 6;
  if ((threadIdx.x & 63) == 0){ s64[wv*4] = w0; s64[wv*4+1] = w1; s64[wv*4+2] = w2; s64[wv*4+3] = w3; }
  __syncthreads();
  float r0 = s64[0], r1 = s64[1], r2 = s64[2], r3 = s64[3];
#pragma unroll
  for (int i = 1; i < 16; ++i){
    r0 = fmaxf(r0, s64[i*4]);   r1 = fmaxf(r1, s64[i*4+1]);
    r2 = fmaxf(r2, s64[i*4+2]); r3 = fmaxf(r3, s64[i*4+3]);
  }
  v[0] = r0; v[1] = r1; v[2] = r2; v[3] = r3;
}

// ---------------- fence-free grid barrier ----------------
// Correctness: all cross-block data moves via sc (MALL-coherent) ops. __syncthreads
// drains vmcnt(0) => every prior sc-store/atomic is complete at the coherence point
// before lane 0 increments the counter. No L2 writeback/invalidate needed.
__device__ __forceinline__ void gbar(int* c){
  __syncthreads();
  if (threadIdx.x == 0){
    __builtin_amdgcn_s_waitcnt(0);   // belt-and-suspenders vmcnt drain
    __hip_atomic_fetch_add(c, 1, __ATOMIC_RELAXED, __HIP_MEMORY_SCOPE_AGENT);
    while (__hip_atomic_load(c, __ATOMIC_RELAXED, __HIP_MEMORY_SCOPE_AGENT) < NB)
      __builtin_amdgcn_s_sleep(2);
  }
  __syncthreads();
}

// ---------------- persistent fused kernel ----------------
// Block B owns rows 4B..4B+3; thread t owns column t. 1 block/CU (86KB LDS), 4 waves/SIMD.
extern "C" __global__ void __launch_bounds__(1024, 4)
__attribute__((amdgpu_waves_per_eu(4, 4)))
gm3(const int* __restrict__ adj1, const int* __restrict__ adj2,
    const float* __restrict__ roW1, const float* __restrict__ roB1,
    const float* __restrict__ roW2, const float* __restrict__ roB2,
    const float* __restrict__ fW1,  const float* __restrict__ fB1,
    const float* __restrict__ fW2,  const float* __restrict__ fB2,
    float* __restrict__ t0, float* __restrict__ t1,
    float* __restrict__ Pp,          // [10][8][N] pre-zeroed column-partial slots
    float* __restrict__ Rg,          // [N] published row factors
    int*   __restrict__ cnt,         // [16] pre-zeroed barrier counters
    float* __restrict__ out)
{
  __shared__ __align__(16) float rows20[20][N];   // 80 KB staging
  __shared__ float lc[N];                         // log C3
  __shared__ float s64[64];
  __shared__ float tab5[8];
  __shared__ float sAv[4];
  __shared__ float ux[64], udA[64], udB[64], xs_s[64], dA_s[64], dB_s[64];
  __shared__ float A_tab[65], B_tab[65], sA0B0[2];

  const int t = threadIdx.x, B = blockIdx.x;
  int bar = 0;

  int a2[KD];
#pragma unroll
  for (int c = 0; c < KD; ++c) a2[c] = adj2[t * KD + c];

  // ---- ttheta (redundant per block, no sync) ----
  {
    int v1[KD];
#pragma unroll
    for (int r = 0; r < KD; ++r) v1[r] = adj1[t * KD + r];
    int c1 = 0;
#pragma unroll
    for (int r = 0; r < KD; ++r){
      bool dup = false;
#pragma unroll
      for (int s = 0; s < r; ++s) dup = dup || (v1[s] == v1[r]);
      c1 += dup ? 0 : 1;
    }
    s64[63] = 0.f;  // (unused slot safety)
    float sum = bsum1((float)c1, s64);
    lc[0] = sum;    // stash temporarily (overwritten later)
  }
  const float tt = lc[0] * (1.0f / 1024.0f);

  // degree of column t in G2
  int c2 = 0;
#pragma unroll
  for (int r = 0; r < KD; ++r){
    bool dup = false;
#pragma unroll
    for (int s = 0; s < r; ++s) dup = dup || (a2[s] == a2[r]);
    c2 += dup ? 0 : 1;
  }
  // degrees of the 4 owned G1 rows (uniform scalar loads)
  float d1r[4];
#pragma unroll
  for (int r = 0; r < 4; ++r){
    int w[KD];
#pragma unroll
    for (int s = 0; s < KD; ++s) w[s] = adj1[(4 * B + r) * KD + s];
    int cc = 0;
#pragma unroll
    for (int x = 0; x < KD; ++x){
      bool dup = false;
#pragma unroll
      for (int s = 0; s < x; ++s) dup = dup || (w[s] == w[x]);
      cc += dup ? 0 : 1;
    }
    d1r[r] = (float)cc;
  }

  // ---- layer-0 MLP: 5 distinct inputs -> exact table ----
  if (t < KD){
    float x = -(float)t / tt;
    float acc = roB2[0];
    for (int k = 0; k < 64; ++k){
      float h = fmaxf(fmaf(x, roW1[k], roB1[k]), 0.f);
      acc = fmaf(h, roW2[k], acc);
    }
    tab5[t] = acc;
  }
  __syncthreads();

  // ---- layer-0 row softmax: t0 (sc), E/R regs, C1 partials ----
  float E[4], R[4], q4[4], y[4], rm[4];
#pragma unroll
  for (int r = 0; r < 4; ++r){ y[r] = tab5[(int)fabsf(d1r[r] - (float)c2)]; rm[r] = y[r]; }
  bmax4(rm, s64);
#pragma unroll
  for (int r = 0; r < 4; ++r){
    float tv = y[r] - rm[r];
    store_sc(&t0[(size_t)(4 * B + r) * N + t], tv);
    E[r] = expf(tv);
    q4[r] = E[r];
  }
  bsum4(q4, s64);
  {
    float cp = 0.f;
#pragma unroll
    for (int r = 0; r < 4; ++r){ R[r] = 1.0f / q4[r]; cp = fmaf(E[r], R[r], cp); }
    atomicAdd(&Pp[(size_t)(0 * 8 + (B & 7)) * N + t], cp);
  }

  const float* tcur = t0;
  float* tnx = t1;
  float yF[4], rmFv[4], rsFv[4];

#pragma unroll 1
  for (int li = 0; li < 3; ++li){
    // ================= barrier 1: C1 partials complete; prev t fully visible =================
    gbar(&cnt[bar]); ++bar;

    // gather the 20 needed t-rows (sc loads from MALL), stash in LDS
#pragma unroll
    for (int r2 = 0; r2 < 20; ++r2){
      int src = adj1[(4 * B + (r2 / 5)) * KD + (r2 % 5)];     // uniform scalar
      rows20[r2][t] = load_sc(&tcur[(size_t)src * N + t]);
    }

    // C1 renorm -> R, publish C2 partials
    {
      int pb = (3 * li + 0) * 8;
      float C = 0.f;
#pragma unroll
      for (int k = 0; k < 8; ++k) C += load_sc(&Pp[(size_t)(pb + k) * N + t]);
      float iC = 1.0f / C;
#pragma unroll
      for (int r = 0; r < 4; ++r) q4[r] = E[r] * iC;
      bsum4(q4, s64);
      float cp = 0.f;
#pragma unroll
      for (int r = 0; r < 4; ++r){ R[r] = 1.0f / q4[r]; cp = fmaf(E[r], R[r], cp); }
      atomicAdd(&Pp[(size_t)(pb + 8 + (B & 7)) * N + t], cp);
    }

    // ================= barrier 2: C2 ready =================
    gbar(&cnt[bar]); ++bar;
    {
      int pb = (3 * li + 1) * 8;
      float C = 0.f;
#pragma unroll
      for (int k = 0; k < 8; ++k) C += load_sc(&Pp[(size_t)(pb + k) * N + t]);
      float iC = 1.0f / C;
#pragma unroll
      for (int r = 0; r < 4; ++r) q4[r] = E[r] * iC;
      bsum4(q4, s64);
      float cp = 0.f;
#pragma unroll
      for (int r = 0; r < 4; ++r){ R[r] = 1.0f / q4[r]; cp = fmaf(E[r], R[r], cp); }
      if (t < 4) store_sc(&Rg[4 * B + t], R[t]);            // publish final R
      atomicAdd(&Pp[(size_t)(pb + 8 + (B & 7)) * N + t], cp);
    }

    // ================= barrier 3: C3 + Rg ready =================
    gbar(&cnt[bar]); ++bar;
    {
      int pb = (3 * li + 2) * 8;
      float C = 0.f;
#pragma unroll
      for (int k = 0; k < 8; ++k) C += load_sc(&Pp[(size_t)(pb + k) * N + t]);
      lc[t] = logf(C);
    }
    // A-terms on wave 1 (lanes 64..67); PWL breakpoints on wave 0
    if (t >= 64 && t < 68){
      int a = 4 * B + (t - 64);
      float s = 5.0f * logf(1536.0f);
#pragma unroll
      for (int r = 0; r < KD; ++r) s += logf(load_sc(&Rg[adj1[a * KD + r]]));
      sAv[t - 64] = s;
    }
    const float* w1g = (li < 2) ? (roW1 + (li + 1) * 64) : fW1;
    const float* b1g = (li < 2) ? (roB1 + (li + 1) * 64) : fB1;
    const float* w2g = (li < 2) ? (roW2 + (li + 1) * 64) : fW2;
    const float* b2g = (li < 2) ? (roB2 + (li + 1))      : fB2;
    if (t < 64){
      float w1 = w1g[t], bb = b1g[t], w2 = w2g[t];
      float xk, sdA, sdB, a0t = 0.f, b0t = 0.f;
      if (w1 != 0.f){
        xk = -bb / w1;
        float dA = w1 * w2, dB = bb * w2;
        if (w1 > 0.f){ sdA = dA;  sdB = dB; }
        else         { sdA = -dA; sdB = -dB; a0t = dA; b0t = dB; }
      } else {
        xk = 3.0e38f; sdA = 0.f; sdB = 0.f;
        b0t = fmaxf(bb, 0.f) * w2;
      }
      ux[t] = xk; udA[t] = sdA; udB[t] = sdB;
      float A0 = wred_sum(a0t);
      float B0 = wred_sum(b0t);
      if (t == 0){ sA0B0[0] = A0; sA0B0[1] = B0 + b2g[0]; }
    }
    __syncthreads();
    if (t < 64){
      float xk = ux[t]; int rank = 0;
      for (int j = 0; j < 64; ++j){
        float xj = ux[j];
        rank += (xj < xk || (xj == xk && j < t)) ? 1 : 0;
      }
      xs_s[rank] = ux[t]; dA_s[rank] = udA[t]; dB_s[rank] = udB[t];
    }
    __syncthreads();
    if (t < 65){
      float sa = sA0B0[0], sb = sA0B0[1];
      for (int r = 0; r < t; ++r){ sa += dA_s[r]; sb += dB_s[r]; }
      A_tab[t] = sa; B_tab[t] = sb;
    }
    __syncthreads();

    // ---- DP assignment-max (register-light, t5 row streamed per popc layer) + PWL ----
    float Bvl = 0.f;
#pragma unroll
    for (int c = 0; c < KD; ++c) Bvl -= lc[a2[c]];
#pragma unroll 1
    for (int rr = 0; rr < 4; ++rr){
      float f[32];
      f[0] = 0.f;
#pragma unroll
      for (int r = 0; r < KD; ++r){
        float tr[KD];
#pragma unroll
        for (int c = 0; c < KD; ++c) tr[c] = rows20[rr * 5 + r][a2[c]];
#pragma unroll
        for (int m = 1; m < 32; ++m){
          if (__popc(m) == r + 1){
            float best = -3.0e38f;
#pragma unroll
            for (int c = 0; c < KD; ++c)
              if (m & (1 << c)) best = fmaxf(best, f[m ^ (1 << c)] + tr[c]);
            f[m] = best;
          }
        }
      }
      float X1v = sAv[rr] + Bvl + f[31];
      float x = (li < 2) ? (X1v / tt) : X1v;
      int seg = 0;
#pragma unroll
      for (int s = 64; s; s >>= 1)
        if (seg + s <= 64 && xs_s[seg + s - 1] <= x) seg += s;
      y[rr] = fmaf(A_tab[seg], x, B_tab[seg]);
      rm[rr] = y[rr];
    }
    bmax4(rm, s64);
    if (li < 2){
#pragma unroll
      for (int r = 0; r < 4; ++r){
        float tv = y[r] - rm[r];
        store_sc(&tnx[(size_t)(4 * B + r) * N + t], tv);
        E[r] = expf(tv);
        q4[r] = E[r];
      }
      bsum4(q4, s64);
      float cp = 0.f;
#pragma unroll
      for (int r = 0; r < 4; ++r){ R[r] = 1.0f / q4[r]; cp = fmaf(E[r], R[r], cp); }
      atomicAdd(&Pp[(size_t)((3 * li + 3) * 8 + (B & 7)) * N + t], cp);
      const float* tmp = tcur; tcur = tnx; tnx = (float*)tmp;
    } else {
      float cp = 0.f;
#pragma unroll
      for (int r = 0; r < 4; ++r){
        yF[r] = y[r]; rmFv[r] = rm[r];
        q4[r] = expf(y[r] - rm[r]);
        cp += expf(y[r]);
      }
      bsum4(q4, s64);
#pragma unroll
      for (int r = 0; r < 4; ++r) rsFv[r] = q4[r];
      atomicAdd(&Pp[(size_t)(9 * 8 + (B & 7)) * N + t], cp);
    }
  }

  // ================= final barrier: CF ready =================
  gbar(&cnt[bar]); ++bar;
  float CF = 0.f;
#pragma unroll
  for (int k = 0; k < 8; ++k) CF += load_sc(&Pp[(size_t)(72 + k) * N + t]);
  float iCF = 1.0f / CF;
#pragma unroll
  for (int r = 0; r < 4; ++r){
    float v = 0.5f * (expf(yF[r] - rmFv[r]) / rsFv[r] + expf(yF[r]) * iCF);
    out[(size_t)(4 * B + r) * N + t] = v;
  }
}

extern "C" void kernel_launch(void* const* d_in, const int* in_sizes, int n_in,
                              void* d_out, int out_size, void* d_ws, size_t ws_size,
                              hipStream_t stream){
  (void)in_sizes; (void)n_in; (void)out_size; (void)ws_size;
  const int*   adj1 = (const int*)d_in[2];
  const int*   adj2 = (const int*)d_in[3];
  const float* roW1 = (const float*)d_in[4];
  const float* roB1 = (const float*)d_in[5];
  const float* roW2 = (const float*)d_in[6];
  const float* roB2 = (const float*)d_in[7];
  const float* fW1  = (const float*)d_in[8];
  const float* fB1  = (const float*)d_in[9];
  const float* fW2  = (const float*)d_in[10];
  const float* fB2  = (const float*)d_in[11];
  float* out = (float*)d_out;

  // ws: t0 (4MB) | t1 (4MB) | Pp 10*8*N (320KB) | Rg N | cnt 16 ints
  float* t0 = (float*)d_ws;
  float* t1 = t0 + (size_t)N * N;
  float* Pp = t1 + (size_t)N * N;
  float* Rg = Pp + (size_t)10 * 8 * N;
  int*  cnt = (int*)(Rg + N);

  // memset completes as its own dispatch -> zeros visible at MALL before gm3's atomics
  hipMemsetAsync(Pp, 0, (10 * 8 * N + N) * sizeof(float) + 16 * sizeof(int), stream);
  gm3<<<NB, 1024, 0, stream>>>(adj1, adj2, roW1, roB1, roW2, roB2,
                               fW1, fB1, fW2, fB2,
                               t0, t1, Pp, Rg, cnt, out);
}

// Round 6
// 183.177 us; speedup vs baseline: 1.7405x; 1.3056x over previous
//
#include <hip/hip_runtime.h>
#include <math.h>

#define N 1024
#define KD 5
#define SL 8   // column-partial slots (atomic fan-in 256/8=32 blocks per address)

// ---------------- wave (64-lane) reductions ----------------
__device__ __forceinline__ float wred_sum(float v){
#pragma unroll
  for (int off = 32; off > 0; off >>= 1) v += __shfl_down(v, off);
  return v;
}
__device__ __forceinline__ float wred_max(float v){
#pragma unroll
  for (int off = 32; off > 0; off >>= 1) v = fmaxf(v, __shfl_down(v, off));
  return v;
}
// ---- 1024-thread block reductions, result broadcast ----
__device__ __forceinline__ float bsum1(float v, float* s64){
  float w = wred_sum(v);
  __syncthreads();
  if ((threadIdx.x & 63) == 0) s64[threadIdx.x >> 6] = w;
  __syncthreads();
  float r = 0.f;
#pragma unroll
  for (int i = 0; i < 16; ++i) r += s64[i];
  return r;
}
__device__ __forceinline__ void bsum4(float v[4], float* s64){
  float w0 = wred_sum(v[0]), w1 = wred_sum(v[1]), w2 = wred_sum(v[2]), w3 = wred_sum(v[3]);
  __syncthreads();
  int wv = threadIdx.x >> 6;
  if ((threadIdx.x & 63) == 0){ s64[wv*4] = w0; s64[wv*4+1] = w1; s64[wv*4+2] = w2; s64[wv*4+3] = w3; }
  __syncthreads();
  float r0 = 0.f, r1 = 0.f, r2 = 0.f, r3 = 0.f;
#pragma unroll
  for (int i = 0; i < 16; ++i){ r0 += s64[i*4]; r1 += s64[i*4+1]; r2 += s64[i*4+2]; r3 += s64[i*4+3]; }
  v[0] = r0; v[1] = r1; v[2] = r2; v[3] = r3;
}
__device__ __forceinline__ void bmax4(float v[4], float* s64){
  float w0 = wred_max(v[0]), w1 = wred_max(v[1]), w2 = wred_max(v[2]), w3 = wred_max(v[3]);
  __syncthreads();
  int wv = threadIdx.x >> 6;
  if ((threadIdx.x & 63) == 0){ s64[wv*4] = w0; s64[wv*4+1] = w1; s64[wv*4+2] = w2; s64[wv*4+3] = w3; }
  __syncthreads();
  float r0 = s64[0], r1 = s64[1], r2 = s64[2], r3 = s64[3];
#pragma unroll
  for (int i = 1; i < 16; ++i){
    r0 = fmaxf(r0, s64[i*4]);   r1 = fmaxf(r1, s64[i*4+1]);
    r2 = fmaxf(r2, s64[i*4+2]); r3 = fmaxf(r3, s64[i*4+3]);
  }
  v[0] = r0; v[1] = r1; v[2] = r2; v[3] = r3;
}

// ---------------- layer-0 producer ----------------
// Block B owns rows 4B..4B+3; thread t owns column t. Computes tt + degrees
// redundantly, exact 5-entry layer-0 MLP table, writes t0 = y0 - rowmax,
// emits C1 column partials.
__global__ __launch_bounds__(1024) void
k_row0(const int* __restrict__ adj1, const int* __restrict__ adj2,
       const float* __restrict__ roW1, const float* __restrict__ roB1,
       const float* __restrict__ roW2, const float* __restrict__ roB2,
       float* __restrict__ t0, float* __restrict__ Pp)
{
  __shared__ float s64[64];
  __shared__ float tab5[8];
  const int t = threadIdx.x, B = blockIdx.x;

  // ttheta (redundant per block)
  int v1[KD];
#pragma unroll
  for (int r = 0; r < KD; ++r) v1[r] = adj1[t * KD + r];
  int c1 = 0;
#pragma unroll
  for (int r = 0; r < KD; ++r){
    bool dup = false;
#pragma unroll
    for (int s = 0; s < r; ++s) dup = dup || (v1[s] == v1[r]);
    c1 += dup ? 0 : 1;
  }
  const float tt = bsum1((float)c1, s64) * (1.0f / 1024.0f);

  // column-t degree in G2
  int a2[KD];
#pragma unroll
  for (int c = 0; c < KD; ++c) a2[c] = adj2[t * KD + c];
  int c2 = 0;
#pragma unroll
  for (int r = 0; r < KD; ++r){
    bool dup = false;
#pragma unroll
    for (int s = 0; s < r; ++s) dup = dup || (a2[s] == a2[r]);
    c2 += dup ? 0 : 1;
  }
  // degrees of 4 owned G1 rows (uniform scalar loads)
  float d1r[4];
#pragma unroll
  for (int r = 0; r < 4; ++r){
    int w[KD];
#pragma unroll
    for (int s = 0; s < KD; ++s) w[s] = adj1[(4 * B + r) * KD + s];
    int cc = 0;
#pragma unroll
    for (int x = 0; x < KD; ++x){
      bool dup = false;
#pragma unroll
      for (int s = 0; s < x; ++s) dup = dup || (w[s] == w[x]);
      cc += dup ? 0 : 1;
    }
    d1r[r] = (float)cc;
  }
  // exact layer-0 MLP table (5 distinct inputs)
  if (t < KD){
    float x = -(float)t / tt;
    float acc = roB2[0];
    for (int k = 0; k < 64; ++k){
      float h = fmaxf(fmaf(x, roW1[k], roB1[k]), 0.f);
      acc = fmaf(h, roW2[k], acc);
    }
    tab5[t] = acc;
  }
  __syncthreads();

  float y[4], rm[4];
#pragma unroll
  for (int r = 0; r < 4; ++r){ y[r] = tab5[(int)fabsf(d1r[r] - (float)c2)]; rm[r] = y[r]; }
  bmax4(rm, s64);
  float e[4], q[4];
#pragma unroll
  for (int r = 0; r < 4; ++r){
    float tv = y[r] - rm[r];
    t0[(size_t)(4 * B + r) * N + t] = tv;
    e[r] = expf(tv);
    q[r] = e[r];
  }
  bsum4(q, s64);
  float cp = 0.f;
#pragma unroll
  for (int r = 0; r < 4; ++r) cp += e[r] / q[r];
  atomicAdd(&Pp[(size_t)(B & (SL - 1)) * N + t], cp);
}

// ---------------- fused sinkhorn pass: renorm rows with Cin, emit Cout partials ----------------
__global__ __launch_bounds__(1024) void
kS(const float* __restrict__ tm, const float* __restrict__ CinB, float* __restrict__ CoutB,
   float* __restrict__ Rg, int writeRg)
{
  __shared__ float s64[64];
  const int t = threadIdx.x, B = blockIdx.x;
  float C = 0.f;
#pragma unroll
  for (int k = 0; k < SL; ++k) C += CinB[(size_t)k * N + t];
  float iC = 1.0f / C;
  float e[4], q[4];
#pragma unroll
  for (int r = 0; r < 4; ++r){
    e[r] = expf(tm[(size_t)(4 * B + r) * N + t]);
    q[r] = e[r] * iC;
  }
  bsum4(q, s64);
  float cp = 0.f;
#pragma unroll
  for (int r = 0; r < 4; ++r) cp += e[r] / q[r];
  atomicAdd(&CoutB[(size_t)(B & (SL - 1)) * N + t], cp);
  if (writeRg && t < 4) Rg[4 * B + t] = 1.0f / q[t];
}

// ---------------- X1 + fused next MLP (PWL) + row stats + next column partials ----------------
// 256 blocks x 1024 threads; block owns rows 4B..4B+3, thread owns column t.
__global__ __launch_bounds__(1024) void
kX1(const float* __restrict__ tm, const int* __restrict__ adj1, const int* __restrict__ adj2,
    const float* __restrict__ Rg, const float* __restrict__ C3B,
    const float* __restrict__ w1g, const float* __restrict__ b1g,
    const float* __restrict__ w2g, const float* __restrict__ b2g,
    int isFinal, float* __restrict__ tnx, float* __restrict__ CoutB,
    float* __restrict__ rmF, float* __restrict__ rsF)
{
  __shared__ __align__(16) float rows20[20][N];   // 80 KB
  __shared__ float lc[N];
  __shared__ float s64[64];
  __shared__ float sAv[4];
  __shared__ float ux[64], udA[64], udB[64], xs_s[64], dA_s[64], dB_s[64];
  __shared__ float A_tab[65], B_tab[65], sA0B0[2];
  const int t = threadIdx.x, B = blockIdx.x;

  // ttheta (redundant; used for li<2 scaling)
  int v1[KD];
#pragma unroll
  for (int r = 0; r < KD; ++r) v1[r] = adj1[t * KD + r];
  int c1 = 0;
#pragma unroll
  for (int r = 0; r < KD; ++r){
    bool dup = false;
#pragma unroll
    for (int s = 0; s < r; ++s) dup = dup || (v1[s] == v1[r]);
    c1 += dup ? 0 : 1;
  }
  const float tt = bsum1((float)c1, s64) * (1.0f / 1024.0f);

  int a2[KD];
#pragma unroll
  for (int c = 0; c < KD; ++c) a2[c] = adj2[t * KD + c];

  // C3 -> log into LDS
  {
    float C = 0.f;
#pragma unroll
    for (int k = 0; k < SL; ++k) C += C3B[(size_t)k * N + t];
    lc[t] = logf(C);
  }
  // stage the 20 gathered t-rows (plain cached loads; ~5x inter-block L2 reuse)
#pragma unroll
  for (int r2 = 0; r2 < 20; ++r2){
    int src = adj1[(4 * B + (r2 / 5)) * KD + (r2 % 5)];   // uniform scalar load
    rows20[r2][t] = tm[(size_t)src * N + t];
  }
  // A-terms on wave 1
  if (t >= 64 && t < 68){
    int a = 4 * B + (t - 64);
    float s = 5.0f * logf(1536.0f);
#pragma unroll
    for (int r = 0; r < KD; ++r) s += logf(Rg[adj1[a * KD + r]]);
    sAv[t - 64] = s;
  }
  // PWL table build on wave 0
  if (t < 64){
    float w1 = w1g[t], bb = b1g[t], w2 = w2g[t];
    float xk, sdA, sdB, a0t = 0.f, b0t = 0.f;
    if (w1 != 0.f){
      xk = -bb / w1;
      float dA = w1 * w2, dB = bb * w2;
      if (w1 > 0.f){ sdA = dA;  sdB = dB; }
      else         { sdA = -dA; sdB = -dB; a0t = dA; b0t = dB; }
    } else {
      xk = 3.0e38f; sdA = 0.f; sdB = 0.f;
      b0t = fmaxf(bb, 0.f) * w2;
    }
    ux[t] = xk; udA[t] = sdA; udB[t] = sdB;
    float A0 = wred_sum(a0t);
    float B0 = wred_sum(b0t);
    if (t == 0){ sA0B0[0] = A0; sA0B0[1] = B0 + b2g[0]; }
  }
  __syncthreads();
  if (t < 64){
    float xk = ux[t]; int rank = 0;
    for (int j = 0; j < 64; ++j){
      float xj = ux[j];
      rank += (xj < xk || (xj == xk && j < t)) ? 1 : 0;
    }
    xs_s[rank] = ux[t]; dA_s[rank] = udA[t]; dB_s[rank] = udB[t];
  }
  __syncthreads();
  if (t < 65){
    float sa = sA0B0[0], sb = sA0B0[1];
    for (int r = 0; r < t; ++r){ sa += dA_s[r]; sb += dB_s[r]; }
    A_tab[t] = sa; B_tab[t] = sb;
  }
  __syncthreads();

  float Bvl = 0.f;
#pragma unroll
  for (int c = 0; c < KD; ++c) Bvl -= lc[a2[c]];

  float y[4], rm[4];
#pragma unroll 1
  for (int rr = 0; rr < 4; ++rr){
    // register-light streamed subset-DP (max live ~ f[32] + tr[5])
    float f[32];
    f[0] = 0.f;
#pragma unroll
    for (int r = 0; r < KD; ++r){
      float tr[KD];
#pragma unroll
      for (int c = 0; c < KD; ++c) tr[c] = rows20[rr * 5 + r][a2[c]];
#pragma unroll
      for (int m = 1; m < 32; ++m){
        if (__popc(m) == r + 1){
          float best = -3.0e38f;
#pragma unroll
          for (int c = 0; c < KD; ++c)
            if (m & (1 << c)) best = fmaxf(best, f[m ^ (1 << c)] + tr[c]);
          f[m] = best;
        }
      }
    }
    float X1v = sAv[rr] + Bvl + f[31];
    float x = isFinal ? X1v : (X1v / tt);
    int seg = 0;
#pragma unroll
    for (int s = 64; s; s >>= 1)
      if (seg + s <= 64 && xs_s[seg + s - 1] <= x) seg += s;
    y[rr] = fmaf(A_tab[seg], x, B_tab[seg]);
    rm[rr] = y[rr];
  }
  bmax4(rm, s64);

  float e[4], q[4];
#pragma unroll
  for (int r = 0; r < 4; ++r){
    e[r] = expf(y[r] - rm[r]);
    q[r] = e[r];
  }
  bsum4(q, s64);
  if (!isFinal){
    float cp = 0.f;
#pragma unroll
    for (int r = 0; r < 4; ++r){
      tnx[(size_t)(4 * B + r) * N + t] = y[r] - rm[r];
      cp += e[r] / q[r];
    }
    atomicAdd(&CoutB[(size_t)(B & (SL - 1)) * N + t], cp);
  } else {
    float cp = 0.f;
#pragma unroll
    for (int r = 0; r < 4; ++r){
      tnx[(size_t)(4 * B + r) * N + t] = y[r];     // unshifted y_final
      cp += expf(y[r]);
    }
    atomicAdd(&CoutB[(size_t)(B & (SL - 1)) * N + t], cp);
    if (t < 4){ rmF[4 * B + t] = rm[t]; rsF[4 * B + t] = q[t]; }
  }
}

// ---------------- final combine: 0.5*(row softmax + col softmax), in place ----------------
__global__ __launch_bounds__(1024) void
k_combine(const float* __restrict__ y, const float* __restrict__ rmF,
          const float* __restrict__ rsF, const float* __restrict__ CFB,
          float* __restrict__ out)
{
  const int t = threadIdx.x, B = blockIdx.x;
  float CF = 0.f;
#pragma unroll
  for (int k = 0; k < SL; ++k) CF += CFB[(size_t)k * N + t];
  float iCF = 1.0f / CF;
#pragma unroll
  for (int r = 0; r < 4; ++r){
    int a = 4 * B + r;
    float yv = y[(size_t)a * N + t];
    float v = 0.5f * (expf(yv - rmF[a]) / rsF[a] + expf(yv) * iCF);
    out[(size_t)a * N + t] = v;
  }
}

extern "C" void kernel_launch(void* const* d_in, const int* in_sizes, int n_in,
                              void* d_out, int out_size, void* d_ws, size_t ws_size,
                              hipStream_t stream){
  (void)in_sizes; (void)n_in; (void)out_size; (void)ws_size;
  const int*   adj1 = (const int*)d_in[2];
  const int*   adj2 = (const int*)d_in[3];
  const float* roW1 = (const float*)d_in[4];
  const float* roB1 = (const float*)d_in[5];
  const float* roW2 = (const float*)d_in[6];
  const float* roB2 = (const float*)d_in[7];
  const float* fW1  = (const float*)d_in[8];
  const float* fB1  = (const float*)d_in[9];
  const float* fW2  = (const float*)d_in[10];
  const float* fB2  = (const float*)d_in[11];
  float* out = (float*)d_out;

  // ws: wsA (4MB) | Pp 10*SL*N (320KB) | Rg N | rmF N | rsF N
  float* wsA = (float*)d_ws;
  float* Pp  = wsA + (size_t)N * N;
  float* Rg  = Pp + (size_t)10 * SL * N;
  float* rmF = Rg + N;
  float* rsF = rmF + N;

  hipMemsetAsync(Pp, 0, (size_t)10 * SL * N * sizeof(float), stream);
  k_row0<<<256, 1024, 0, stream>>>(adj1, adj2, roW1, roB1, roW2, roB2, wsA, Pp);

  for (int li = 0; li < 3; ++li){
    const float* tcur = (li == 1) ? out : wsA;    // ping-pong: t0=wsA, t1=out, t2=wsA
    float* tnx        = (li == 1) ? wsA : out;
    float* Ca = Pp + (size_t)(3 * li + 0) * SL * N;
    float* Cb = Pp + (size_t)(3 * li + 1) * SL * N;
    float* Cc = Pp + (size_t)(3 * li + 2) * SL * N;
    kS<<<256, 1024, 0, stream>>>(tcur, Ca, Cb, Rg, 0);
    kS<<<256, 1024, 0, stream>>>(tcur, Cb, Cc, Rg, 1);
    int isFinal = (li == 2);
    const float* w1 = isFinal ? fW1 : roW1 + (li + 1) * 64;
    const float* b1 = isFinal ? fB1 : roB1 + (li + 1) * 64;
    const float* w2 = isFinal ? fW2 : roW2 + (li + 1) * 64;
    const float* b2 = isFinal ? fB2 : roB2 + (li + 1);
    float* CoutNext = isFinal ? (Pp + (size_t)9 * SL * N) : (Pp + (size_t)(3 * li + 3) * SL * N);
    kX1<<<256, 1024, 0, stream>>>(tcur, adj1, adj2, Rg, Cc,
                                  w1, b1, w2, b2, isFinal, tnx, CoutNext, rmF, rsF);
  }
  k_combine<<<256, 1024, 0, stream>>>(out, rmF, rsF, Pp + (size_t)9 * SL * N, out);
}